// Round 1
// baseline (219.833 us; speedup 1.0000x reference)
//
#include <hip/hip_runtime.h>

#define N 8192
#define M 4
#define L 256
#define HDR 64  // header floats in ws: [0]=n_events [1]=kl_joint [2]=kl_mod [3]=S_joint [4..7]=S_mod

// ws float layout:
//   [0..HDR)                  accumulators (zeroed via hipMemsetAsync)
//   [HDR .. HDR+N)            exph_joint
//   [HDR+N .. HDR+N+M*N)      exph_mod (row-major m,N)
//   [HDR+N+M*N .. +N)         time (packed from target[:,0])

__device__ inline float waveReduceSum(float v) {
    #pragma unroll
    for (int off = 32; off > 0; off >>= 1) v += __shfl_down(v, off, 64);
    return v;
}

__global__ __launch_bounds__(256) void prep_kl_kernel(
    const float* __restrict__ jlh, const float* __restrict__ mlh,
    const float4* __restrict__ jloc, const float4* __restrict__ jscale,
    const float4* __restrict__ mloc, const float4* __restrict__ mscale,
    const float* __restrict__ target, float* __restrict__ ws)
{
    const int tid = blockIdx.x * blockDim.x + threadIdx.x;
    const int nth = gridDim.x * blockDim.x;
    float* exph_j = ws + HDR;
    float* exph_m = ws + HDR + N;
    float* timev  = ws + HDR + N + M * N;

    // exp(modality hazards)
    for (int i = tid; i < M * N; i += nth) exph_m[i] = __expf(mlh[i]);

    // exp(joint hazard), packed time, event count
    float ev = 0.f;
    for (int i = tid; i < N; i += nth) {
        exph_j[i] = __expf(jlh[i]);
        timev[i]  = target[2 * i];
        ev += target[2 * i + 1];
    }

    // KL sums (natural log): -log(s) + 0.5*(s^2 + l^2 - 1)
    float kj = 0.f;
    for (int i = tid; i < (N * L) / 4; i += nth) {
        float4 l = jloc[i], s = jscale[i];
        kj += 0.5f * (s.x * s.x + l.x * l.x) - __logf(s.x) - 0.5f;
        kj += 0.5f * (s.y * s.y + l.y * l.y) - __logf(s.y) - 0.5f;
        kj += 0.5f * (s.z * s.z + l.z * l.z) - __logf(s.z) - 0.5f;
        kj += 0.5f * (s.w * s.w + l.w * l.w) - __logf(s.w) - 0.5f;
    }
    float km = 0.f;
    for (int i = tid; i < (M * N * L) / 4; i += nth) {
        float4 l = mloc[i], s = mscale[i];
        km += 0.5f * (s.x * s.x + l.x * l.x) - __logf(s.x) - 0.5f;
        km += 0.5f * (s.y * s.y + l.y * l.y) - __logf(s.y) - 0.5f;
        km += 0.5f * (s.z * s.z + l.z * l.z) - __logf(s.z) - 0.5f;
        km += 0.5f * (s.w * s.w + l.w * l.w) - __logf(s.w) - 0.5f;
    }

    // block reduce 3 values
    __shared__ float sm[3][4];
    ev = waveReduceSum(ev);
    kj = waveReduceSum(kj);
    km = waveReduceSum(km);
    const int lane = threadIdx.x & 63, wid = threadIdx.x >> 6;
    if (lane == 0) { sm[0][wid] = ev; sm[1][wid] = kj; sm[2][wid] = km; }
    __syncthreads();
    if (threadIdx.x == 0) {
        atomicAdd(&ws[0], sm[0][0] + sm[0][1] + sm[0][2] + sm[0][3]);
        atomicAdd(&ws[1], sm[1][0] + sm[1][1] + sm[1][2] + sm[1][3]);
        atomicAdd(&ws[2], sm[2][0] + sm[2][1] + sm[2][2] + sm[2][3]);
    }
}

// 256 blocks x 256 threads. Block b owns rows i = b*32 .. b*32+31.
// Thread layout: il = tid&31 (which row), g = tid>>5 (which 1/8 of the j-range).
__global__ __launch_bounds__(256) void cox_kernel(
    const float* __restrict__ jlh, const float* __restrict__ mlh,
    const float* __restrict__ target, float* __restrict__ ws)
{
    const float* exph_j = ws + HDR;
    const float* exph_m = ws + HDR + N;
    const float* timev  = ws + HDR + N + M * N;

    const int tid = threadIdx.x;
    const int il  = tid & 31;
    const int g   = tid >> 5;              // 0..7
    const int i   = blockIdx.x * 32 + il;
    const float t_i = timev[i];

    const float4* tv = (const float4*)timev;
    const float4* e0 = (const float4*)exph_j;
    const float4* e1 = (const float4*)(exph_m);
    const float4* e2 = (const float4*)(exph_m + N);
    const float4* e3 = (const float4*)(exph_m + 2 * N);
    const float4* e4 = (const float4*)(exph_m + 3 * N);

    float a0 = 0.f, a1 = 0.f, a2 = 0.f, a3 = 0.f, a4 = 0.f;
    const int chunk = (N / 4) / 8;         // 256 float4 per group
    const int vbeg = g * chunk, vend = vbeg + chunk;
    #pragma unroll 2
    for (int v = vbeg; v < vend; ++v) {
        float4 t = tv[v];
        float m0 = (t.x >= t_i) ? 1.f : 0.f;
        float m1 = (t.y >= t_i) ? 1.f : 0.f;
        float m2 = (t.z >= t_i) ? 1.f : 0.f;
        float m3 = (t.w >= t_i) ? 1.f : 0.f;
        float4 x;
        x = e0[v]; a0 += m0 * x.x + m1 * x.y + m2 * x.z + m3 * x.w;
        x = e1[v]; a1 += m0 * x.x + m1 * x.y + m2 * x.z + m3 * x.w;
        x = e2[v]; a2 += m0 * x.x + m1 * x.y + m2 * x.z + m3 * x.w;
        x = e3[v]; a3 += m0 * x.x + m1 * x.y + m2 * x.z + m3 * x.w;
        x = e4[v]; a4 += m0 * x.x + m1 * x.y + m2 * x.z + m3 * x.w;
    }

    __shared__ float part[8][32][5];
    part[g][il][0] = a0; part[g][il][1] = a1; part[g][il][2] = a2;
    part[g][il][3] = a3; part[g][il][4] = a4;
    __shared__ float contrib[32][5];
    __syncthreads();

    if (tid < 32) {
        float r0 = 0.f, r1 = 0.f, r2 = 0.f, r3 = 0.f, r4 = 0.f;
        #pragma unroll
        for (int gg = 0; gg < 8; ++gg) {
            r0 += part[gg][il][0]; r1 += part[gg][il][1]; r2 += part[gg][il][2];
            r3 += part[gg][il][3]; r4 += part[gg][il][4];
        }
        const float ev = target[2 * i + 1];
        contrib[il][0] = ev * (jlh[i]         - __logf(r0));
        contrib[il][1] = ev * (mlh[0 * N + i] - __logf(r1));
        contrib[il][2] = ev * (mlh[1 * N + i] - __logf(r2));
        contrib[il][3] = ev * (mlh[2 * N + i] - __logf(r3));
        contrib[il][4] = ev * (mlh[3 * N + i] - __logf(r4));
    }
    __syncthreads();
    if (tid == 0) {
        float s0 = 0.f, s1 = 0.f, s2 = 0.f, s3 = 0.f, s4 = 0.f;
        for (int k = 0; k < 32; ++k) {
            s0 += contrib[k][0]; s1 += contrib[k][1]; s2 += contrib[k][2];
            s3 += contrib[k][3]; s4 += contrib[k][4];
        }
        atomicAdd(&ws[3], s0);
        atomicAdd(&ws[4], s1);
        atomicAdd(&ws[5], s2);
        atomicAdd(&ws[6], s3);
        atomicAdd(&ws[7], s4);
    }
}

__global__ void finalize_kernel(const float* __restrict__ ws,
                                const float* __restrict__ alpha_p,
                                const float* __restrict__ beta_p,
                                float* __restrict__ out)
{
    const float nev = ws[0];
    const float klj = ws[1] / (float)N;
    const float klm = ws[2] / (float)N;
    const float Sj  = ws[3];
    const float Sm  = ws[4] + ws[5] + ws[6] + ws[7];
    const float alpha = alpha_p[0], beta = beta_p[0];
    out[0] = -Sj / nev + beta * klj + alpha * (-Sm / nev + beta * klm);
}

extern "C" void kernel_launch(void* const* d_in, const int* in_sizes, int n_in,
                              void* d_out, int out_size, void* d_ws, size_t ws_size,
                              hipStream_t stream) {
    const float* jlh    = (const float*)d_in[0];  // (N,)
    const float* mlh    = (const float*)d_in[1];  // (M,N)
    const float* jloc   = (const float*)d_in[2];  // (N,L)
    const float* jscale = (const float*)d_in[3];  // (N,L)
    const float* mloc   = (const float*)d_in[4];  // (M,N,L)
    const float* mscale = (const float*)d_in[5];  // (M,N,L)
    const float* target = (const float*)d_in[6];  // (N,2)
    const float* alpha  = (const float*)d_in[7];
    const float* beta   = (const float*)d_in[8];
    float* out = (float*)d_out;
    float* ws  = (float*)d_ws;

    hipMemsetAsync(ws, 0, HDR * sizeof(float), stream);

    prep_kl_kernel<<<1024, 256, 0, stream>>>(
        jlh, mlh, (const float4*)jloc, (const float4*)jscale,
        (const float4*)mloc, (const float4*)mscale, target, ws);

    cox_kernel<<<256, 256, 0, stream>>>(jlh, mlh, target, ws);

    finalize_kernel<<<1, 1, 0, stream>>>(ws, alpha, beta, out);
}

// Round 2
// 147.309 us; speedup vs baseline: 1.4923x; 1.4923x over previous
//
#include <hip/hip_runtime.h>

#define N 8192
#define M 4
#define L 256
#define CBLK 1024        // cox blocks
#define TOTBLK 2048      // + 1024 KL blocks
#define ROWS 8           // rows per cox block
#define THREADS 256
#define WS_COX 0         // ws[0 .. 5*CBLK): cox partials, stream-major [5][CBLK]
#define WS_KL (5 * CBLK) // ws[5120 .. 5120+2*CBLK): kl partials [2][CBLK]

__device__ __forceinline__ float waveSum(float v) {
#pragma unroll
    for (int off = 32; off > 0; off >>= 1) v += __shfl_down(v, off, 64);
    return v;
}

__device__ __forceinline__ float4 exp4(float4 h) {
    return make_float4(__expf(h.x), __expf(h.y), __expf(h.z), __expf(h.w));
}

__device__ __forceinline__ float kl4(float4 l, float4 s) {
    float k;
    k  = 0.5f * (s.x * s.x + l.x * l.x) - __logf(s.x) - 0.5f;
    k += 0.5f * (s.y * s.y + l.y * l.y) - __logf(s.y) - 0.5f;
    k += 0.5f * (s.z * s.z + l.z * l.z) - __logf(s.z) - 0.5f;
    k += 0.5f * (s.w * s.w + l.w * l.w) - __logf(s.w) - 0.5f;
    return k;
}

__global__ __launch_bounds__(THREADS) void fused_kernel(
    const float* __restrict__ jlh, const float* __restrict__ mlh,
    const float4* __restrict__ jloc4, const float4* __restrict__ jscale4,
    const float4* __restrict__ mloc4, const float4* __restrict__ mscale4,
    const float* __restrict__ target, float* __restrict__ ws)
{
    const int tid = threadIdx.x;

    if (blockIdx.x < CBLK) {
        // ---------------- Cox path ----------------
        __shared__ float red[4][ROWS][5];
        __shared__ float cr[5][ROWS];
        const int b = blockIdx.x;
        const int i0 = b * ROWS;

        float t_i[ROWS];
#pragma unroll
        for (int r = 0; r < ROWS; ++r) t_i[r] = target[2 * (i0 + r)];

        float acc[ROWS][5];
#pragma unroll
        for (int r = 0; r < ROWS; ++r)
#pragma unroll
            for (int s = 0; s < 5; ++s) acc[r][s] = 0.f;

        const float4* tg4 = (const float4*)target;
        const float4* jl4 = (const float4*)jlh;
        const float4* m04 = (const float4*)(mlh);
        const float4* m14 = (const float4*)(mlh + N);
        const float4* m24 = (const float4*)(mlh + 2 * N);
        const float4* m34 = (const float4*)(mlh + 3 * N);

#pragma unroll 2
        for (int g = 0; g < N / (THREADS * 4); ++g) {   // 8 quad-groups/thread
            const int q = g * THREADS + tid;            // float4 index in [0, 2048)
            const float4 f1 = tg4[2 * q];
            const float4 f2 = tg4[2 * q + 1];
            const float4 tj = make_float4(f1.x, f1.z, f2.x, f2.z);
            const float4 e0 = exp4(jl4[q]);
            const float4 e1 = exp4(m04[q]);
            const float4 e2 = exp4(m14[q]);
            const float4 e3 = exp4(m24[q]);
            const float4 e4 = exp4(m34[q]);
#pragma unroll
            for (int r = 0; r < ROWS; ++r) {
                const float ti = t_i[r];
                const float m0 = (tj.x >= ti) ? 1.f : 0.f;
                const float m1 = (tj.y >= ti) ? 1.f : 0.f;
                const float m2 = (tj.z >= ti) ? 1.f : 0.f;
                const float m3 = (tj.w >= ti) ? 1.f : 0.f;
                acc[r][0] = fmaf(m0, e0.x, fmaf(m1, e0.y, fmaf(m2, e0.z, fmaf(m3, e0.w, acc[r][0]))));
                acc[r][1] = fmaf(m0, e1.x, fmaf(m1, e1.y, fmaf(m2, e1.z, fmaf(m3, e1.w, acc[r][1]))));
                acc[r][2] = fmaf(m0, e2.x, fmaf(m1, e2.y, fmaf(m2, e2.z, fmaf(m3, e2.w, acc[r][2]))));
                acc[r][3] = fmaf(m0, e3.x, fmaf(m1, e3.y, fmaf(m2, e3.z, fmaf(m3, e3.w, acc[r][3]))));
                acc[r][4] = fmaf(m0, e4.x, fmaf(m1, e4.y, fmaf(m2, e4.z, fmaf(m3, e4.w, acc[r][4]))));
            }
        }

        // reduce across the 256 threads
#pragma unroll
        for (int r = 0; r < ROWS; ++r)
#pragma unroll
            for (int s = 0; s < 5; ++s) acc[r][s] = waveSum(acc[r][s]);

        const int lane = tid & 63, wid = tid >> 6;
        if (lane == 0) {
#pragma unroll
            for (int r = 0; r < ROWS; ++r)
#pragma unroll
                for (int s = 0; s < 5; ++s) red[wid][r][s] = acc[r][s];
        }
        __syncthreads();

        if (tid < ROWS * 5) {
            const int r = tid / 5, s = tid % 5;
            const float risk = red[0][r][s] + red[1][r][s] + red[2][r][s] + red[3][r][s];
            const float ev = target[2 * (i0 + r) + 1];
            const float h = (s == 0) ? jlh[i0 + r] : mlh[(s - 1) * N + i0 + r];
            cr[s][r] = ev * (h - __logf(risk));
        }
        __syncthreads();

        if (tid < 5) {
            float v = 0.f;
#pragma unroll
            for (int r = 0; r < ROWS; ++r) v += cr[tid][r];
            ws[WS_COX + tid * CBLK + b] = v;
        }
    } else {
        // ---------------- KL path (pure streaming) ----------------
        __shared__ float kred[2][4];
        const int kb = blockIdx.x - CBLK;
        float kj = 0.f, km = 0.f;
#pragma unroll
        for (int it = 0; it < 2; ++it) {            // joint: 512 f4/block
            const int idx = kb * 512 + it * THREADS + tid;
            kj += kl4(jloc4[idx], jscale4[idx]);
        }
#pragma unroll
        for (int it = 0; it < 8; ++it) {            // modality: 2048 f4/block
            const int idx = kb * 2048 + it * THREADS + tid;
            km += kl4(mloc4[idx], mscale4[idx]);
        }
        kj = waveSum(kj);
        km = waveSum(km);
        const int lane = tid & 63, wid = tid >> 6;
        if (lane == 0) { kred[0][wid] = kj; kred[1][wid] = km; }
        __syncthreads();
        if (tid == 0)
            ws[WS_KL + kb] = kred[0][0] + kred[0][1] + kred[0][2] + kred[0][3];
        if (tid == 1)
            ws[WS_KL + CBLK + kb] = kred[1][0] + kred[1][1] + kred[1][2] + kred[1][3];
    }
}

__global__ __launch_bounds__(THREADS) void finalize_kernel(
    const float* __restrict__ target, const float* __restrict__ ws,
    const float* __restrict__ alpha_p, const float* __restrict__ beta_p,
    float* __restrict__ out)
{
    const int tid = threadIdx.x;
    float ev = 0.f;
    for (int i = tid; i < N; i += THREADS) ev += target[2 * i + 1];
    float s0 = 0.f, s1 = 0.f, s2 = 0.f, s3 = 0.f, s4 = 0.f, kj = 0.f, km = 0.f;
    for (int i = tid; i < CBLK; i += THREADS) {
        s0 += ws[0 * CBLK + i];
        s1 += ws[1 * CBLK + i];
        s2 += ws[2 * CBLK + i];
        s3 += ws[3 * CBLK + i];
        s4 += ws[4 * CBLK + i];
        kj += ws[WS_KL + i];
        km += ws[WS_KL + CBLK + i];
    }
    ev = waveSum(ev); s0 = waveSum(s0); s1 = waveSum(s1); s2 = waveSum(s2);
    s3 = waveSum(s3); s4 = waveSum(s4); kj = waveSum(kj); km = waveSum(km);

    __shared__ float red[8][4];
    const int lane = tid & 63, wid = tid >> 6;
    if (lane == 0) {
        red[0][wid] = ev; red[1][wid] = s0; red[2][wid] = s1; red[3][wid] = s2;
        red[4][wid] = s3; red[5][wid] = s4; red[6][wid] = kj; red[7][wid] = km;
    }
    __syncthreads();
    if (tid == 0) {
        float v[8];
#pragma unroll
        for (int k = 0; k < 8; ++k) v[k] = red[k][0] + red[k][1] + red[k][2] + red[k][3];
        const float EV = v[0];
        const float alpha = alpha_p[0], beta = beta_p[0];
        const float cox_j = -v[1] / EV;
        const float cox_m = -(v[2] + v[3] + v[4] + v[5]) / EV;
        out[0] = cox_j + beta * (v[6] / (float)N) + alpha * (cox_m + beta * (v[7] / (float)N));
    }
}

extern "C" void kernel_launch(void* const* d_in, const int* in_sizes, int n_in,
                              void* d_out, int out_size, void* d_ws, size_t ws_size,
                              hipStream_t stream) {
    const float* jlh    = (const float*)d_in[0];  // (N,)
    const float* mlh    = (const float*)d_in[1];  // (M,N)
    const float* jloc   = (const float*)d_in[2];  // (N,L)
    const float* jscale = (const float*)d_in[3];  // (N,L)
    const float* mloc   = (const float*)d_in[4];  // (M,N,L)
    const float* mscale = (const float*)d_in[5];  // (M,N,L)
    const float* target = (const float*)d_in[6];  // (N,2)
    const float* alpha  = (const float*)d_in[7];
    const float* beta   = (const float*)d_in[8];
    float* out = (float*)d_out;
    float* ws  = (float*)d_ws;

    fused_kernel<<<TOTBLK, THREADS, 0, stream>>>(
        jlh, mlh, (const float4*)jloc, (const float4*)jscale,
        (const float4*)mloc, (const float4*)mscale, target, ws);

    finalize_kernel<<<1, THREADS, 0, stream>>>(target, ws, alpha, beta, out);
}